// Round 1
// baseline (176.448 us; speedup 1.0000x reference)
//
#include <hip/hip_runtime.h>

#define B_   8
#define KB_  16
#define SEQ_ 512
#define HID_ 768

typedef __attribute__((ext_vector_type(4))) _Float16 half4;
typedef __attribute__((ext_vector_type(8))) _Float16 half8;
typedef __attribute__((ext_vector_type(4))) float    floatx4;

// ---------------- prepass: row L2-norm reciprocals + fp16 convert ----------------
// one wave per row; 12288 rows total (Q rows then K rows)
__global__ __launch_bounds__(256)
void prep_kernel(const float* __restrict__ Q, const float* __restrict__ K,
                 _Float16* __restrict__ Qh, _Float16* __restrict__ Kh,
                 float* __restrict__ rn)
{
    int row  = blockIdx.x * 4 + (threadIdx.x >> 6);
    int lane = threadIdx.x & 63;
    const float* src;
    _Float16*    dst;
    if (row < B_ * SEQ_) { src = Q + (size_t)row * HID_;              dst = Qh + (size_t)row * HID_; }
    else                 { src = K + (size_t)(row - B_*SEQ_) * HID_;  dst = Kh + (size_t)(row - B_*SEQ_) * HID_; }

    float4 v[3];
    float s = 0.f;
#pragma unroll
    for (int it = 0; it < 3; ++it) {
        v[it] = *(const float4*)(src + lane * 4 + it * 256);
        s += v[it].x * v[it].x + v[it].y * v[it].y + v[it].z * v[it].z + v[it].w * v[it].w;
    }
#pragma unroll
    for (int m = 1; m < 64; m <<= 1) s += __shfl_xor(s, m, 64);
#pragma unroll
    for (int it = 0; it < 3; ++it) {
        half4 h = { (_Float16)v[it].x, (_Float16)v[it].y, (_Float16)v[it].z, (_Float16)v[it].w };
        *(half4*)(dst + lane * 4 + it * 256) = h;
    }
    if (lane == 0) rn[row] = 1.0f / fmaxf(sqrtf(s), 1e-12f);
}

// ---------------- fused GEMM + online softmax + score reduction ----------------
#define BM  128
#define BN  128
#define BK  32
#define LDH 40   // LDS row stride in halves: 16B-aligned frag reads, <=2-way bank conflict (free)

__global__ __launch_bounds__(256, 2)
void li_mfma(const _Float16* __restrict__ Qh, const _Float16* __restrict__ Kh,
             const float* __restrict__ rn, const float* __restrict__ alpha_p,
             const int* __restrict__ qmask, const int* __restrict__ kmask,
             float* __restrict__ out)
{
    const int st = blockIdx.x;   // s tile (0..3)
    const int j  = blockIdx.y;   // key batch (0..15)
    const int i  = blockIdx.z;   // query batch (0..7)

    const _Float16* Qi = Qh + ((size_t)i * SEQ_ + st * BM) * HID_;
    const _Float16* Kj = Kh + (size_t)j * SEQ_ * HID_;
    const float* rq = rn + i * SEQ_ + st * BM;
    const float* rk = rn + B_ * SEQ_ + j * SEQ_;
    const int*   qm = qmask + i * SEQ_ + st * BM;
    const int*   km = kmask + j * SEQ_;

    __shared__ _Float16 Qs[BM * LDH];
    __shared__ _Float16 Ks[BN * LDH];
    __shared__ float red[16];

    const int tid  = threadIdx.x;
    const int lane = tid & 63;
    const int wave = tid >> 6;
    const int quad = lane >> 4;
    const int l16  = lane & 15;

    const float araw  = *alpha_p;
    const float alpha = araw >= 0.f ? araw : 0.01f * araw;   // leaky_relu

    // epilogue rows: s_loc = wave*32 + rt*16 + quad*4 + r  (C/D layout: row=quad*4+reg)
    float rqv[2][4]; int qmv[2][4];
    float m_run[2][4], l_run[2][4], n_run[2][4];
#pragma unroll
    for (int rt = 0; rt < 2; ++rt)
#pragma unroll
        for (int r = 0; r < 4; ++r) {
            int s_loc = wave * 32 + rt * 16 + quad * 4 + r;
            rqv[rt][r]   = rq[s_loc];
            qmv[rt][r]   = qm[s_loc];
            m_run[rt][r] = -INFINITY;
            l_run[rt][r] = 0.f;
            n_run[rt][r] = 0.f;
        }

    // staging: 128 rows x 32 halves per matrix; thread handles rows sr0 and sr0+64 at koff sk0
    const int sr0 = tid >> 2;
    const int sk0 = (tid & 3) * 8;

    for (int t0 = 0; t0 < SEQ_; t0 += BN) {
        floatx4 acc[2][8];
#pragma unroll
        for (int rt = 0; rt < 2; ++rt)
#pragma unroll
            for (int ct = 0; ct < 8; ++ct)
                acc[rt][ct] = (floatx4){0.f, 0.f, 0.f, 0.f};

        for (int k0 = 0; k0 < HID_; k0 += BK) {
            half8 q0  = *(const half8*)(Qi + (size_t)sr0 * HID_ + k0 + sk0);
            half8 q1  = *(const half8*)(Qi + (size_t)(sr0 + 64) * HID_ + k0 + sk0);
            half8 kv0 = *(const half8*)(Kj + (size_t)(t0 + sr0) * HID_ + k0 + sk0);
            half8 kv1 = *(const half8*)(Kj + (size_t)(t0 + sr0 + 64) * HID_ + k0 + sk0);
            __syncthreads();
            *(half8*)(Qs + sr0 * LDH + sk0)        = q0;
            *(half8*)(Qs + (sr0 + 64) * LDH + sk0) = q1;
            *(half8*)(Ks + sr0 * LDH + sk0)        = kv0;
            *(half8*)(Ks + (sr0 + 64) * LDH + sk0) = kv1;
            __syncthreads();

            half8 af[2], bf[8];
#pragma unroll
            for (int rt = 0; rt < 2; ++rt)
                af[rt] = *(const half8*)(Qs + (wave * 32 + rt * 16 + l16) * LDH + quad * 8);
#pragma unroll
            for (int ct = 0; ct < 8; ++ct)
                bf[ct] = *(const half8*)(Ks + (ct * 16 + l16) * LDH + quad * 8);
#pragma unroll
            for (int rt = 0; rt < 2; ++rt)
#pragma unroll
                for (int ct = 0; ct < 8; ++ct)
                    acc[rt][ct] = __builtin_amdgcn_mfma_f32_16x16x32_f16(af[rt], bf[ct], acc[rt][ct], 0, 0, 0);
        }

        // ---- epilogue for this t-tile: online softmax update ----
        float rkv[8]; int kmv[8]; float tgf[8];
#pragma unroll
        for (int ct = 0; ct < 8; ++ct) {
            int t_loc = ct * 16 + l16;
            rkv[ct] = rk[t0 + t_loc];
            kmv[ct] = km[t0 + t_loc];
            tgf[ct] = (float)(t0 + t_loc);
        }
#pragma unroll
        for (int rt = 0; rt < 2; ++rt) {
#pragma unroll
            for (int r = 0; r < 4; ++r) {
                float sgf = (float)(st * BM + wave * 32 + rt * 16 + quad * 4 + r);
                float cv[8], w[8];
                float tmax = -INFINITY;
#pragma unroll
                for (int ct = 0; ct < 8; ++ct) {
                    cv[ct] = acc[rt][ct][r] * rqv[rt][r] * rkv[ct];
                    float d = fabsf(sgf - tgf[ct]);
                    w[ct] = kmv[ct] ? cv[ct] * __expf(-alpha * d) : -INFINITY;
                    tmax = fmaxf(tmax, w[ct]);
                }
#pragma unroll
                for (int msk = 1; msk < 16; msk <<= 1)
                    tmax = fmaxf(tmax, __shfl_xor(tmax, msk, 64));
                float m_new = fmaxf(m_run[rt][r], tmax);
                if (m_new != -INFINITY) {   // quad-uniform branch; shuffles stay within quad
                    float ps = 0.f, ns = 0.f;
#pragma unroll
                    for (int ct = 0; ct < 8; ++ct) {
                        float e = __expf(w[ct] - m_new);   // exp(-inf)=0 handles masked cols
                        ps += e;
                        ns += e * cv[ct];
                    }
#pragma unroll
                    for (int msk = 1; msk < 16; msk <<= 1) {
                        ps += __shfl_xor(ps, msk, 64);
                        ns += __shfl_xor(ns, msk, 64);
                    }
                    float sc = __expf(m_run[rt][r] - m_new);
                    l_run[rt][r] = l_run[rt][r] * sc + ps;
                    n_run[rt][r] = n_run[rt][r] * sc + ns;
                    m_run[rt][r] = m_new;
                }
            }
        }
    }

    // final per-row score = num/l (0 if no valid key or q_mask==0); sum rows -> out[i,j]
    float rsum = 0.f;
#pragma unroll
    for (int rt = 0; rt < 2; ++rt)
#pragma unroll
        for (int r = 0; r < 4; ++r) {
            float scv = (l_run[rt][r] > 0.f) ? n_run[rt][r] / l_run[rt][r] : 0.f;
            if (qmv[rt][r] == 0) scv = 0.f;
            rsum += scv;
        }
    if (l16 == 0) red[wave * 4 + quad] = rsum;   // 16 lanes: 4 waves x 4 quads
    __syncthreads();
    if (tid == 0) {
        float s = 0.f;
#pragma unroll
        for (int x = 0; x < 16; ++x) s += red[x];
        atomicAdd(out + i * KB_ + j, s);
    }
}

extern "C" void kernel_launch(void* const* d_in, const int* in_sizes, int n_in,
                              void* d_out, int out_size, void* d_ws, size_t ws_size,
                              hipStream_t stream)
{
    const float* Q       = (const float*)d_in[0];
    const float* K       = (const float*)d_in[1];
    const float* alpha_p = (const float*)d_in[2];
    const int*   qmask   = (const int*)d_in[3];
    const int*   kmask   = (const int*)d_in[4];
    float*       out     = (float*)d_out;

    char* ws = (char*)d_ws;
    _Float16* Qh = (_Float16*)ws;
    _Float16* Kh = (_Float16*)(ws + (size_t)B_ * SEQ_ * HID_ * 2);
    float*    rn = (float*)   (ws + (size_t)(B_ + KB_) * SEQ_ * HID_ * 2);

    hipMemsetAsync(d_out, 0, (size_t)out_size * sizeof(float), stream);

    prep_kernel<<<(B_ + KB_) * SEQ_ / 4, 256, 0, stream>>>(Q, K, Qh, Kh, rn);

    dim3 grid(SEQ_ / BM, KB_, B_);
    li_mfma<<<grid, 256, 0, stream>>>(Qh, Kh, rn, alpha_p, qmask, kmask, out);
}

// Round 2
// 167.237 us; speedup vs baseline: 1.0551x; 1.0551x over previous
//
#include <hip/hip_runtime.h>

#define B_   8
#define KB_  16
#define SEQ_ 512
#define HID_ 768

typedef __attribute__((ext_vector_type(4))) _Float16 half4;
typedef __attribute__((ext_vector_type(8))) _Float16 half8;
typedef __attribute__((ext_vector_type(4))) float    floatx4;

// ---------------- prepass: L2-normalize rows (fp32) -> fp16 ----------------
// one wave per row; 12288 rows total (Q rows then K rows)
__global__ __launch_bounds__(256)
void prep_kernel(const float* __restrict__ Q, const float* __restrict__ K,
                 _Float16* __restrict__ Qh, _Float16* __restrict__ Kh)
{
    int row  = blockIdx.x * 4 + (threadIdx.x >> 6);
    int lane = threadIdx.x & 63;
    const float* src;
    _Float16*    dst;
    if (row < B_ * SEQ_) { src = Q + (size_t)row * HID_;              dst = Qh + (size_t)row * HID_; }
    else                 { src = K + (size_t)(row - B_*SEQ_) * HID_;  dst = Kh + (size_t)(row - B_*SEQ_) * HID_; }

    float4 v[3];
    float s = 0.f;
#pragma unroll
    for (int it = 0; it < 3; ++it) {
        v[it] = *(const float4*)(src + lane * 4 + it * 256);
        s += v[it].x * v[it].x + v[it].y * v[it].y + v[it].z * v[it].z + v[it].w * v[it].w;
    }
#pragma unroll
    for (int m = 1; m < 64; m <<= 1) s += __shfl_xor(s, m, 64);
    float sc = 1.0f / fmaxf(sqrtf(s), 1e-12f);
#pragma unroll
    for (int it = 0; it < 3; ++it) {
        half4 h = { (_Float16)(v[it].x * sc), (_Float16)(v[it].y * sc),
                    (_Float16)(v[it].z * sc), (_Float16)(v[it].w * sc) };
        *(half4*)(dst + lane * 4 + it * 256) = h;
    }
}

// ---------------- phase 1: per-(i,j,s-tile,t-tile) GEMM + softmax partials ----------------
#define BM  128
#define BN  128
#define BK  32
#define LDH 40   // LDS row stride in halves

__global__ __launch_bounds__(256, 3)
void li_part(const _Float16* __restrict__ Qh, const _Float16* __restrict__ Kh,
             const float* __restrict__ alpha_p, const int* __restrict__ kmask,
             float* __restrict__ Pbuf)
{
    const int st = blockIdx.x >> 2;   // s tile (0..3)
    const int tb = blockIdx.x & 3;    // t tile (0..3)
    const int j  = blockIdx.y;        // key batch
    const int i  = blockIdx.z;        // query batch

    const _Float16* Qi = Qh + ((size_t)i * SEQ_ + st * BM) * HID_;
    const _Float16* Kj = Kh + ((size_t)j * SEQ_ + tb * BN) * HID_;
    const int* km = kmask + j * SEQ_ + tb * BN;

    __shared__ _Float16 Qs[BM * LDH];
    __shared__ _Float16 Ks[BN * LDH];
    __shared__ float pm[2][BM], pl[2][BM], pn[2][BM];

    const int tid  = threadIdx.x;
    const int lane = tid & 63;
    const int wave = tid >> 6;
    const int quad = lane >> 4;
    const int l16  = lane & 15;
    const int wr   = wave >> 1;   // wave row-half (0/1)
    const int wc   = wave & 1;    // wave col-half (0/1)

    const float araw  = *alpha_p;
    const float alpha = araw >= 0.f ? araw : 0.01f * araw;   // leaky_relu

    floatx4 acc[4][4];
#pragma unroll
    for (int rt = 0; rt < 4; ++rt)
#pragma unroll
        for (int ct = 0; ct < 4; ++ct)
            acc[rt][ct] = (floatx4){0.f, 0.f, 0.f, 0.f};

    const int sr0 = tid >> 2;
    const int sk0 = (tid & 3) * 8;

    for (int k0 = 0; k0 < HID_; k0 += BK) {
        half8 q0  = *(const half8*)(Qi + (size_t)sr0 * HID_ + k0 + sk0);
        half8 q1  = *(const half8*)(Qi + (size_t)(sr0 + 64) * HID_ + k0 + sk0);
        half8 kv0 = *(const half8*)(Kj + (size_t)sr0 * HID_ + k0 + sk0);
        half8 kv1 = *(const half8*)(Kj + (size_t)(sr0 + 64) * HID_ + k0 + sk0);
        __syncthreads();
        *(half8*)(Qs + sr0 * LDH + sk0)        = q0;
        *(half8*)(Qs + (sr0 + 64) * LDH + sk0) = q1;
        *(half8*)(Ks + sr0 * LDH + sk0)        = kv0;
        *(half8*)(Ks + (sr0 + 64) * LDH + sk0) = kv1;
        __syncthreads();

        half8 af[4], bf[4];
#pragma unroll
        for (int rt = 0; rt < 4; ++rt)
            af[rt] = *(const half8*)(Qs + (wr * 64 + rt * 16 + l16) * LDH + quad * 8);
#pragma unroll
        for (int ct = 0; ct < 4; ++ct)
            bf[ct] = *(const half8*)(Ks + (wc * 64 + ct * 16 + l16) * LDH + quad * 8);
#pragma unroll
        for (int rt = 0; rt < 4; ++rt)
#pragma unroll
            for (int ct = 0; ct < 4; ++ct)
                acc[rt][ct] = __builtin_amdgcn_mfma_f32_16x16x32_f16(af[rt], bf[ct], acc[rt][ct], 0, 0, 0);
    }

    // ---- epilogue: per-row softmax partial (m, l, n) over this 128-col t-tile ----
    int kmv[4]; float tgf[4];
#pragma unroll
    for (int ct = 0; ct < 4; ++ct) {
        int t_loc = wc * 64 + ct * 16 + l16;
        kmv[ct] = km[t_loc];
        tgf[ct] = (float)(tb * BN + t_loc);
    }
#pragma unroll
    for (int rt = 0; rt < 4; ++rt) {
#pragma unroll
        for (int r = 0; r < 4; ++r) {
            float sgf = (float)(st * BM + wr * 64 + rt * 16 + quad * 4 + r);
            float cv[4], w[4];
            float tmax = -INFINITY;
#pragma unroll
            for (int ct = 0; ct < 4; ++ct) {
                cv[ct] = acc[rt][ct][r];
                float d = fabsf(sgf - tgf[ct]);
                w[ct] = kmv[ct] ? cv[ct] * __expf(-alpha * d) : -INFINITY;
                tmax = fmaxf(tmax, w[ct]);
            }
#pragma unroll
            for (int msk = 1; msk < 16; msk <<= 1)
                tmax = fmaxf(tmax, __shfl_xor(tmax, msk, 64));
            float ps = 0.f, ns = 0.f;
            if (tmax != -INFINITY) {   // quad-uniform; shuffles stay within quad
#pragma unroll
                for (int ct = 0; ct < 4; ++ct) {
                    float e = __expf(w[ct] - tmax);   // exp(-inf)=0 handles masked cols
                    ps += e;
                    ns += e * cv[ct];
                }
#pragma unroll
                for (int msk = 1; msk < 16; msk <<= 1) {
                    ps += __shfl_xor(ps, msk, 64);
                    ns += __shfl_xor(ns, msk, 64);
                }
            }
            if (l16 == 0) {
                int rloc = wr * 64 + rt * 16 + quad * 4 + r;
                pm[wc][rloc] = tmax;
                pl[wc][rloc] = ps;
                pn[wc][rloc] = ns;
            }
        }
    }
    __syncthreads();

    // merge the two col-half waves; write one (m,l,n) partial per row per t-tile
    if (tid < BM) {
        float m0 = pm[0][tid], m1 = pm[1][tid];
        float M = fmaxf(m0, m1);
        float l = 0.f, n = 0.f;
        if (M != -INFINITY) {
            float e0 = __expf(m0 - M), e1 = __expf(m1 - M);
            l = pl[0][tid] * e0 + pl[1][tid] * e1;
            n = pn[0][tid] * e0 + pn[1][tid] * e1;
        }
        size_t base = (((size_t)(i * KB_ + j) * SEQ_) + st * BM + tid) * 12 + tb * 3;
        Pbuf[base]     = M;
        Pbuf[base + 1] = l;
        Pbuf[base + 2] = n;
    }
}

// ---------------- phase 2: merge t-tile partials, apply q_mask, reduce over s ----------------
__global__ __launch_bounds__(256)
void li_reduce(const float* __restrict__ Pbuf, const int* __restrict__ qmask,
               float* __restrict__ out)
{
    const int ij = blockIdx.x;
    const int i  = ij >> 4;           // KB_ == 16
    const int tid = threadIdx.x;
    __shared__ float red[4];

    float sum = 0.f;
#pragma unroll
    for (int rep = 0; rep < 2; ++rep) {
        int s = tid + rep * 256;
        const float4* p = (const float4*)(Pbuf + ((size_t)ij * SEQ_ + s) * 12);
        float4 a = p[0], b = p[1], c = p[2];
        // layout per row: [m0,l0,n0, m1,l1,n1, m2,l2,n2, m3,l3,n3]
        float M = fmaxf(fmaxf(a.x, a.w), fmaxf(b.z, c.y));
        float sc = 0.f;
        if (M != -INFINITY) {
            float e0 = __expf(a.x - M), e1 = __expf(a.w - M);
            float e2 = __expf(b.z - M), e3 = __expf(c.y - M);
            float l = a.y * e0 + b.x * e1 + b.w * e2 + c.z * e3;
            float n = a.z * e0 + b.y * e1 + c.x * e2 + c.w * e3;
            sc = (l > 0.f) ? n / l : 0.f;
        }
        if (qmask[i * SEQ_ + s] == 0) sc = 0.f;
        sum += sc;
    }
#pragma unroll
    for (int m = 1; m < 64; m <<= 1) sum += __shfl_xor(sum, m, 64);
    if ((tid & 63) == 0) red[tid >> 6] = sum;
    __syncthreads();
    if (tid == 0) out[ij] = red[0] + red[1] + red[2] + red[3];
}

extern "C" void kernel_launch(void* const* d_in, const int* in_sizes, int n_in,
                              void* d_out, int out_size, void* d_ws, size_t ws_size,
                              hipStream_t stream)
{
    const float* Q       = (const float*)d_in[0];
    const float* K       = (const float*)d_in[1];
    const float* alpha_p = (const float*)d_in[2];
    const int*   qmask   = (const int*)d_in[3];
    const int*   kmask   = (const int*)d_in[4];
    float*       out     = (float*)d_out;

    char* ws = (char*)d_ws;
    _Float16* Qh   = (_Float16*)ws;
    _Float16* Kh   = (_Float16*)(ws + (size_t)B_ * SEQ_ * HID_ * 2);
    float*    Pbuf = (float*)   (ws + (size_t)(B_ + KB_) * SEQ_ * HID_ * 2);

    prep_kernel<<<(B_ + KB_) * SEQ_ / 4, 256, 0, stream>>>(Q, K, Qh, Kh);

    dim3 grid(16, KB_, B_);   // (st*4+tb, j, i)
    li_part<<<grid, 256, 0, stream>>>(Qh, Kh, alpha_p, kmask, Pbuf);

    li_reduce<<<B_ * KB_, 256, 0, stream>>>(Pbuf, qmask, out);
}